// Round 15
// baseline (382.744 us; speedup 1.0000x reference)
//
#include <hip/hip_runtime.h>
#include <hip/hip_bf16.h>
#include <hip/hip_fp8.h>

// LightGCN forward: fused convert+bucketed CSR build (2048 blocks, 17.6 KB
// LDS -> 8 blk/CU single generation; LDS-staged multisplit, 768-row buckets,
// line-aligned 64B runs, flush-phase pads, bcur holds per-bucket fill
// offsets memset to 0) + per-bucket row reorder (rows padded to x8) + 3-hop
// pull SpMM (wave = 4 edge-groups x 16 dim-lanes, 8 rec/group/iter) +
// InfoNCE loss (block partials + separate finalize; no device fences).

#define NUM_USERS 100000
#define NUM_ITEMS 50000
#define NTOT      150000
#define DIM       64
#define NNZ_C     4000000
#define BATCH     4096
#define NUM_NEG   8
#define NSLICE    (BATCH + BATCH + NUM_NEG * BATCH)   // 40960 hop-3 rows

#define RPB        768                                 // rows per bucket
#define NBUCKET    ((NTOT + RPB - 1) / RPB)            // 196
#define CAP        29440                               // brec region; mean 27576 (incl pads), +10 sigma
#define CAPC       24832                               // crec region; pad8 mean ~23330, +9 sigma
#define BIN_BLOCKS 2048
#define EPB        ((NNZ_C + BIN_BLOCKS - 1) / BIN_BLOCKS)   // 1954
#define NQUAD      (NTOT * DIM / 4)                    // 2.4M x0 quads
#define NLOSSB     (BATCH * 64 / 256)                  // 1024 loss blocks
#define SCALE_ST   3.0517578125e-5f                    // 16 * 2^-19 (x16/hop, w-scale fold)

using fp8t = __hip_fp8_e4m3;

typedef unsigned int u32x4 __attribute__((ext_vector_type(4)));
typedef float        f32x2 __attribute__((ext_vector_type(2)));

__device__ __forceinline__ float f8dec(unsigned char b) {
    fp8t h; h.__x = (__hip_fp8_storage_t)b; return (float)h;
}
__device__ __forceinline__ unsigned char f8enc(float f) {
    fp8t h(f); return (unsigned char)h.__x;
}

// decode 4 packed fp8 (one dword) and fma into acc[0..3] with weight w
__device__ __forceinline__ void fp8x4_fma(unsigned int q, float w, float* a) {
#if __has_builtin(__builtin_amdgcn_cvt_pk_f32_fp8)
    f32x2 lo = __builtin_amdgcn_cvt_pk_f32_fp8((int)q, false);
    f32x2 hi = __builtin_amdgcn_cvt_pk_f32_fp8((int)q, true);
    a[0] = fmaf(w, lo.x, a[0]);
    a[1] = fmaf(w, lo.y, a[1]);
    a[2] = fmaf(w, hi.x, a[2]);
    a[3] = fmaf(w, hi.y, a[3]);
#else
    a[0] = fmaf(w, f8dec((unsigned char)(q       & 0xFF)), a[0]);
    a[1] = fmaf(w, f8dec((unsigned char)((q>>8)  & 0xFF)), a[1]);
    a[2] = fmaf(w, f8dec((unsigned char)((q>>16) & 0xFF)), a[2]);
    a[3] = fmaf(w, f8dec((unsigned char)((q>>24) & 0xFF)), a[3]);
#endif
}

// ---- fused bin pass: x0 convert prologue + LDS multisplit -> flush --------
// Record: int2{ (v14<<18)|col , (b<<18)|row }. Runs rounded to 8 records
// (64B); sentinel pads {0,-1} written in flush phase (lines dirtied once).
// bcur[b*16] holds the bucket fill OFFSET (memset to 0 before launch).
__global__ void __launch_bounds__(256) bin_k(const float* __restrict__ ue,
                                             const float* __restrict__ ie,
                                             unsigned char* __restrict__ x0,
                                             const int* __restrict__ rows,
                                             const int* __restrict__ cols,
                                             const float* __restrict__ vals,
                                             int* __restrict__ bcur,
                                             int2* __restrict__ brec) {
    __shared__ int2 stage[EPB];                    // 15.6 KB (sm overlays head)
    __shared__ int  lh[NBUCKET], gbase[NBUCKET];   // 1.6 KB
    __shared__ unsigned short lofs[NBUCKET];       // 0.4 KB
    int t = threadIdx.x;
    int* sm = (int*)stage;                         // scan scratch, dead before stage use
    int e0 = blockIdx.x * EPB;
    int e1 = e0 + EPB; if (e1 > NNZ_C) e1 = NNZ_C;
    for (int i = t; i < NBUCKET; i += 256) lh[i] = 0;
    // convert prologue: grid-stride x0 = fp8(concat(ue, ie)) — independent
    for (int i = blockIdx.x * 256 + t; i < NQUAD; i += BIN_BLOCKS * 256) {
        float4 v = (i * 4 < NUM_USERS * DIM)
                       ? ((const float4*)ue)[i]
                       : ((const float4*)ie)[i - NUM_USERS * DIM / 4];
        uchar4 o;
        o.x = f8enc(v.x); o.y = f8enc(v.y); o.z = f8enc(v.z); o.w = f8enc(v.w);
        ((uchar4*)x0)[i] = o;
    }
    __syncthreads();
    #pragma unroll 4
    for (int e = e0 + t; e < e1; e += 256)
        atomicAdd(&lh[rows[e] / RPB], 1);          // cached: re-read in scatter
    __syncthreads();
    {   // exclusive scan of lh -> lofs (NBUCKET=196 <= 256: 1 elem/thread)
        int ssum = (t < NBUCKET) ? lh[t] : 0;
        sm[t] = ssum;
        __syncthreads();
        for (int o = 1; o < 256; o <<= 1) {
            int v = (t >= o) ? sm[t - o] : 0;
            __syncthreads();
            sm[t] += v;
            __syncthreads();
        }
        if (t < NBUCKET) lofs[t] = (unsigned short)(sm[t] - ssum);
    }
    __syncthreads();
    for (int i = t; i < NBUCKET; i += 256) {
        int c = lh[i];
        if (c) {
            int c8 = (c + 7) & ~7;                      // line-align the run
            gbase[i] = i * CAP + atomicAdd(&bcur[i * 16], c8);
        }
        lh[i] = 0;
    }
    __syncthreads();
    #pragma unroll 2
    for (int e = e0 + t; e < e1; e += 256) {
        int   r = rows[e];                              // L2-warm (hist read)
        int   c = __builtin_nontemporal_load(cols + e);
        float v = __builtin_nontemporal_load(vals + e);
        int b = r / RPB;
        int rank = atomicAdd(&lh[b], 1);
        int j = (int)lofs[b] + rank;
        unsigned int v14 = (unsigned int)lrintf(v * 524288.0f);   // x 2^19
        if (v14 > 16383u) v14 = 16383u;
        stage[j] = make_int2((int)((v14 << 18) | (unsigned int)c),
                             (b << 18) | r);            // bucket packed in .y
    }
    __syncthreads();
    int cnt = e1 - e0;
    for (int j = t; j < cnt; j += 256) {
        int2 rc = stage[j];
        int b = (int)((unsigned int)rc.y >> 18);        // no div in flush
        brec[gbase[b] + (j - (int)lofs[b])] = rc;
    }
    // pad tails: written while the payload lines are still L2-dirty
    for (int i = t; i < NBUCKET; i += 256) {
        int c = lh[i];
        if (c) {
            int c8 = (c + 7) & ~7;
            int g  = gbase[i];
            for (int q = g + c; q < g + c8; ++q)
                brec[q] = make_int2(0, -1);
        }
    }
}

// ---- per-bucket reorder -> crec (rows padded to x8, zero-filled pads) -----
// 768-row buckets, 512 threads, 196 blocks = single generation.
__global__ void __launch_bounds__(512) csr_fix_k(const int2* __restrict__ brec,
                                                 const int* __restrict__ bcur,
                                                 unsigned int* __restrict__ crec,
                                                 int2* __restrict__ rp2) {
    __shared__ int lh[RPB], lb[RPB], lc[RPB], sm2[512];
    int b = blockIdx.x;
    int t = threadIdx.x;
    int s = b * CAP;
    int cnt = bcur[b * 16];                         // fill offset = count
    int cb = b * CAPC;
    int rbase = b * RPB;
    for (int i = t; i < RPB; i += 512) lh[i] = 0;
    __syncthreads();
    for (int j = t; j < cnt; j += 512) {
        unsigned int rl = (unsigned int)((brec[s + j].y & 0x3FFFF) - rbase);
        if (rl < RPB) atomicAdd(&lh[rl], 1);         // sentinel pads skipped
    }
    __syncthreads();
    {   // exclusive scan of pad8 counts -> lb; write rp2, zero lc (K=2)
        int loc[2];
        int ssum = 0;
        #pragma unroll
        for (int k = 0; k < 2; ++k) {
            int i = t * 2 + k;
            loc[k] = (i < RPB) ? ((lh[i] + 7) & ~7) : 0;
            ssum += loc[k];
        }
        sm2[t] = ssum;
        __syncthreads();
        for (int o = 1; o < 512; o <<= 1) {
            int v = (t >= o) ? sm2[t - o] : 0;
            __syncthreads();
            sm2[t] += v;
            __syncthreads();
        }
        int run = sm2[t] - ssum;
        #pragma unroll
        for (int k = 0; k < 2; ++k) {
            int i = t * 2 + k;
            if (i < RPB) {
                lb[i] = run;
                lc[i] = 0;
                int row = rbase + i;
                if (row < NTOT) rp2[row] = make_int2(cb + run, cb + run + lh[i]);
            }
            run += loc[k];
        }
    }
    __syncthreads();
    for (int j = t; j < cnt; j += 512) {
        int2 rc = brec[s + j];
        unsigned int rl = (unsigned int)((rc.y & 0x3FFFF) - rbase);
        if (rl < RPB) {
            int pos = atomicAdd(&lc[rl], 1);
            crec[cb + lb[rl] + pos] = (unsigned int)rc.x;   // pre-quantized
        }
    }
    __syncthreads();
    // zero-fill pad slots [lh, cnt8) per row (disjoint from record writes)
    for (int i = t; i < RPB; i += 512) {
        int base = cb + lb[i];
        int c8 = (lh[i] + 7) & ~7;
        for (int q = lh[i]; q < c8; ++q) crec[base + q] = 0u;
    }
}

// ---- pull-mode SpMM body: wave = 4 edge-groups x 16 dim-lanes -------------
// Group g = lane>>4 owns record slots [j+8g, j+8g+8); lane&15 owns dim quad.
// Weights kept as integer-valued floats; 2^-19 scale folded into the store.
__device__ __forceinline__ void spmm_row_v4(const unsigned char* __restrict__ x,
                                            const unsigned int* __restrict__ crec,
                                            int s, int e, int lane, float* acc) {
    int g  = lane >> 4;
    int dq = (lane & 15) * 4;
    acc[0] = acc[1] = acc[2] = acc[3] = 0.0f;
    int e8 = s + ((e - s + 7) & ~7);         // padded end (zero records in pads)
    for (int j = s + 8 * g; j < e8; j += 32) {
        u32x4 pa = __builtin_nontemporal_load((const u32x4*)(crec + j));
        u32x4 pb = __builtin_nontemporal_load((const u32x4*)(crec + j + 4));
        unsigned int q0 = *(const unsigned int*)(x + (pa.x & 0x3FFFFu) * DIM + dq);
        unsigned int q1 = *(const unsigned int*)(x + (pa.y & 0x3FFFFu) * DIM + dq);
        unsigned int q2 = *(const unsigned int*)(x + (pa.z & 0x3FFFFu) * DIM + dq);
        unsigned int q3 = *(const unsigned int*)(x + (pa.w & 0x3FFFFu) * DIM + dq);
        unsigned int q4 = *(const unsigned int*)(x + (pb.x & 0x3FFFFu) * DIM + dq);
        unsigned int q5 = *(const unsigned int*)(x + (pb.y & 0x3FFFFu) * DIM + dq);
        unsigned int q6 = *(const unsigned int*)(x + (pb.z & 0x3FFFFu) * DIM + dq);
        unsigned int q7 = *(const unsigned int*)(x + (pb.w & 0x3FFFFu) * DIM + dq);
        float w0 = (float)(pa.x >> 18);
        float w1 = (float)(pa.y >> 18);
        float w2 = (float)(pa.z >> 18);
        float w3 = (float)(pa.w >> 18);
        float w4 = (float)(pb.x >> 18);
        float w5 = (float)(pb.y >> 18);
        float w6 = (float)(pb.z >> 18);
        float w7 = (float)(pb.w >> 18);
        fp8x4_fma(q0, w0, acc);
        fp8x4_fma(q1, w1, acc);
        fp8x4_fma(q2, w2, acc);
        fp8x4_fma(q3, w3, acc);
        fp8x4_fma(q4, w4, acc);
        fp8x4_fma(q5, w5, acc);
        fp8x4_fma(q6, w6, acc);
        fp8x4_fma(q7, w7, acc);
    }
    // combine the 4 edge-groups: butterfly over lane bits 4,5
    acc[0] += __shfl_xor(acc[0], 16, 64);
    acc[1] += __shfl_xor(acc[1], 16, 64);
    acc[2] += __shfl_xor(acc[2], 16, 64);
    acc[3] += __shfl_xor(acc[3], 16, 64);
    acc[0] += __shfl_xor(acc[0], 32, 64);
    acc[1] += __shfl_xor(acc[1], 32, 64);
    acc[2] += __shfl_xor(acc[2], 32, 64);
    acc[3] += __shfl_xor(acc[3], 32, 64);
}

__device__ __forceinline__ void spmm_store(unsigned char* __restrict__ y, int row,
                                           int lane, const float* acc) {
    if (lane < 16) {
        uchar4 o;
        o.x = f8enc(acc[0] * SCALE_ST);
        o.y = f8enc(acc[1] * SCALE_ST);
        o.z = f8enc(acc[2] * SCALE_ST);
        o.w = f8enc(acc[3] * SCALE_ST);
        *(uchar4*)(y + row * DIM + lane * 4) = o;
    }
}

// ---- full SpMM: one wave per row; output scaled x16 -----------------------
__global__ void spmm_k(const unsigned char* __restrict__ x, const int2* __restrict__ rp2,
                       const unsigned int* __restrict__ crec, unsigned char* __restrict__ y) {
    int row  = (blockIdx.x * blockDim.x + threadIdx.x) >> 6;
    int lane = threadIdx.x & 63;
    if (row >= NTOT) return;
    int2 se = rp2[row];
    float acc[4];
    spmm_row_v4(x, crec, se.x, se.y, lane, acc);
    spmm_store(y, row, lane, acc);
}

// ---- sliced SpMM for hop 3: only rows the loss reads ----------------------
__global__ void spmm_sliced_k(const unsigned char* __restrict__ x, const int2* __restrict__ rp2,
                              const unsigned int* __restrict__ crec,
                              const int* __restrict__ users, const int* __restrict__ items,
                              const int* __restrict__ negs, unsigned char* __restrict__ y) {
    int w    = (blockIdx.x * blockDim.x + threadIdx.x) >> 6;
    int lane = threadIdx.x & 63;
    if (w >= NSLICE) return;
    int row = (w < BATCH)     ? users[w]
            : (w < 2 * BATCH) ? NUM_USERS + items[w - BATCH]
                              : NUM_USERS + negs[w - 2 * BATCH];
    int2 se = rp2[row];
    float acc[4];
    spmm_row_v4(x, crec, se.x, se.y, lane, acc);
    spmm_store(y, row, lane, acc);   // duplicate rows rewrite same value: benign
}

// ---- InfoNCE loss; e = 0.25*(x0 + x1/16 + x2/256 + x3/4096) ---------------
// Atomic-free: per-block LDS reduce -> plain store to partials[block].
__global__ void loss_k(const unsigned char* __restrict__ x0, const unsigned char* __restrict__ x1,
                       const unsigned char* __restrict__ x2, const unsigned char* __restrict__ x3,
                       const int* __restrict__ users, const int* __restrict__ items,
                       const int* __restrict__ negs, float* __restrict__ partials) {
    __shared__ float psum[4];
    int w    = (blockIdx.x * blockDim.x + threadIdx.x) >> 6;
    int lane = threadIdx.x & 63;
    int wv   = threadIdx.x >> 6;
    float v = 0.0f;
    if (w < BATCH) {
        auto rowv = [&](int r) -> float {
            int o = r * DIM + lane;
            return 0.25f * f8dec(x0[o]) + 0.015625f * f8dec(x1[o]) +
                   9.765625e-4f * f8dec(x2[o]) + 6.103515625e-5f * f8dec(x3[o]);
        };
        float ue = rowv(users[w]);
        float ie = rowv(NUM_USERS + items[w]);
        float p = ue * ie;
        for (int o = 32; o > 0; o >>= 1) p += __shfl_xor(p, o, 64);
        float pe = expf(p);
        float ne = 0.0f;
        for (int k = 0; k < NUM_NEG; ++k) {
            float q = ue * rowv(NUM_USERS + negs[k * BATCH + w]);
            for (int o = 32; o > 0; o >>= 1) q += __shfl_xor(q, o, 64);
            ne += expf(q);
        }
        v = logf((pe + ne) / pe);
    }
    if (lane == 0) psum[wv] = v;
    __syncthreads();
    if (threadIdx.x == 0)
        partials[blockIdx.x] = psum[0] + psum[1] + psum[2] + psum[3];
}

// ---- final reduce: one block sums NLOSSB partials ------------------------
__global__ void finalize_k(const float* __restrict__ partials, float* __restrict__ out) {
    __shared__ float ps[4];
    int t = threadIdx.x;
    float s = 0.0f;
    for (int i = t; i < NLOSSB; i += 256) s += partials[i];
    for (int o = 32; o > 0; o >>= 1) s += __shfl_xor(s, o, 64);
    if ((t & 63) == 0) ps[t >> 6] = s;
    __syncthreads();
    if (t == 0) out[0] = (ps[0] + ps[1] + ps[2] + ps[3]) * (1.0f / BATCH);
}

__global__ void sentinel_k(float* __restrict__ out) {
    out[0] = -1.0f;
}

extern "C" void kernel_launch(void* const* d_in, const int* in_sizes, int n_in,
                              void* d_out, int out_size, void* d_ws, size_t ws_size,
                              hipStream_t stream) {
    const float* user_emb = (const float*)d_in[0];
    const float* item_emb = (const float*)d_in[1];
    const float* A_vals   = (const float*)d_in[2];
    const int*   A_rows   = (const int*)d_in[3];
    const int*   A_cols   = (const int*)d_in[4];
    const int*   users    = (const int*)d_in[5];
    const int*   items    = (const int*)d_in[6];
    const int*   negs     = (const int*)d_in[7];
    float* out = (float*)d_out;

    char* ws = (char*)d_ws;
    size_t off = 0;
    auto carve = [&](size_t bytes) -> char* {
        char* p = ws + off;
        off = (off + bytes + 255) & ~(size_t)255;
        return p;
    };
    unsigned char* x0 = (unsigned char*)carve((size_t)NTOT * DIM);    // 9.6 MB
    unsigned char* x1 = (unsigned char*)carve((size_t)NTOT * DIM);
    unsigned char* x2 = (unsigned char*)carve((size_t)NTOT * DIM);
    unsigned char* x3 = (unsigned char*)carve((size_t)NTOT * DIM);
    int2*  brec       = (int2*)carve((size_t)NBUCKET * CAP * 8);      // 46.2 MB
    unsigned int* crec= (unsigned int*)carve((size_t)NBUCKET * CAPC * 4 + 1024); // 19.5 MB
    int2*  rp2        = (int2*)carve((size_t)NTOT * 8);               //  1.2 MB
    int*   bcur       = (int*)carve((size_t)NBUCKET * 64);            // 64B-strided fill offsets
    float* partials   = (float*)carve((size_t)NLOSSB * 4);            // 4 KB

    if (off > ws_size) {
        sentinel_k<<<1, 1, 0, stream>>>(out);
        return;
    }

    // bcur holds per-bucket fill offsets: zero-init (graph-capture-safe)
    hipMemsetAsync(bcur, 0, (size_t)NBUCKET * 64, stream);

    // fused convert + bucketed build, then per-bucket row reorder
    bin_k<<<BIN_BLOCKS, 256, 0, stream>>>(user_emb, item_emb, x0,
                                          A_rows, A_cols, A_vals, bcur, brec);
    csr_fix_k<<<NBUCKET, 512, 0, stream>>>(brec, bcur, crec, rp2);

    // hops 1-2 full, hop 3 sliced to loss rows
    const int spmm_blocks = (NTOT * 64 + 255) / 256;
    spmm_k<<<spmm_blocks, 256, 0, stream>>>(x0, rp2, crec, x1);
    spmm_k<<<spmm_blocks, 256, 0, stream>>>(x1, rp2, crec, x2);
    spmm_sliced_k<<<(NSLICE * 64 + 255) / 256, 256, 0, stream>>>(x2, rp2, crec, users, items, negs, x3);

    // loss: block partials (no atomics) + single-block reduce
    loss_k<<<NLOSSB, 256, 0, stream>>>(x0, x1, x2, x3, users, items, negs, partials);
    finalize_k<<<1, 256, 0, stream>>>(partials, out);
}

// Round 16
// 359.125 us; speedup vs baseline: 1.0658x; 1.0658x over previous
//
#include <hip/hip_runtime.h>
#include <hip/hip_bf16.h>
#include <hip/hip_fp8.h>

// LightGCN forward: bucketed CSR build (LDS-staged multisplit, 768-row
// buckets, line-aligned 64B runs, flush-phase pads, bucket-id packed in
// record.y) + per-bucket row reorder (rows padded to x8) + 3-hop pull SpMM
// (wave = 4 edge-groups x 16 dim-lanes, 8 rec/group/iter, weight-scale
// hoisted to store) + InfoNCE loss (block partials, separate finalize).
// REVERT to round-14 optimum: r15's 2048-block bin + fused convert regressed
// (pad traffic doubled, embed reads serialized into bin's phase chain).

#define NUM_USERS 100000
#define NUM_ITEMS 50000
#define NTOT      150000
#define DIM       64
#define NNZ_C     4000000
#define BATCH     4096
#define NUM_NEG   8
#define NSLICE    (BATCH + BATCH + NUM_NEG * BATCH)   // 40960 hop-3 rows

#define RPB        768                                 // rows per bucket
#define NBUCKET    ((NTOT + RPB - 1) / RPB)            // 196
#define CAP        25600                               // brec region; mean 23992 (incl line pads), +11 sigma
#define CAPC       24832                               // crec region; pad8 mean ~23330, +9 sigma
#define BIN_BLOCKS 1024
#define EPB        ((NNZ_C + BIN_BLOCKS - 1) / BIN_BLOCKS)   // 3907
#define NLOSSB     (BATCH * 64 / 256)                  // 1024 loss blocks
#define SCALE_ST   3.0517578125e-5f                    // 16 * 2^-19 (x16/hop, w-scale fold)

using fp8t = __hip_fp8_e4m3;

typedef unsigned int u32x4 __attribute__((ext_vector_type(4)));
typedef float        f32x2 __attribute__((ext_vector_type(2)));

__device__ __forceinline__ float f8dec(unsigned char b) {
    fp8t h; h.__x = (__hip_fp8_storage_t)b; return (float)h;
}
__device__ __forceinline__ unsigned char f8enc(float f) {
    fp8t h(f); return (unsigned char)h.__x;
}

// decode 4 packed fp8 (one dword) and fma into acc[0..3] with weight w
__device__ __forceinline__ void fp8x4_fma(unsigned int q, float w, float* a) {
#if __has_builtin(__builtin_amdgcn_cvt_pk_f32_fp8)
    f32x2 lo = __builtin_amdgcn_cvt_pk_f32_fp8((int)q, false);
    f32x2 hi = __builtin_amdgcn_cvt_pk_f32_fp8((int)q, true);
    a[0] = fmaf(w, lo.x, a[0]);
    a[1] = fmaf(w, lo.y, a[1]);
    a[2] = fmaf(w, hi.x, a[2]);
    a[3] = fmaf(w, hi.y, a[3]);
#else
    a[0] = fmaf(w, f8dec((unsigned char)(q       & 0xFF)), a[0]);
    a[1] = fmaf(w, f8dec((unsigned char)((q>>8)  & 0xFF)), a[1]);
    a[2] = fmaf(w, f8dec((unsigned char)((q>>16) & 0xFF)), a[2]);
    a[3] = fmaf(w, f8dec((unsigned char)((q>>24) & 0xFF)), a[3]);
#endif
}

// ---- x0 = fp8(concat(user_emb, item_emb)); init bcur ----------------------
__global__ void convert_concat(const float* __restrict__ ue, const float* __restrict__ ie,
                               unsigned char* __restrict__ x0, int* __restrict__ bcur) {
    int i = blockIdx.x * blockDim.x + threadIdx.x;   // quad index
    if (i < NBUCKET) bcur[i * 16] = i * CAP;         // 64B-strided cursors
    if (i >= NTOT * DIM / 4) return;
    float4 v = (i * 4 < NUM_USERS * DIM)
                   ? ((const float4*)ue)[i]
                   : ((const float4*)ie)[i - NUM_USERS * DIM / 4];
    uchar4 o;
    o.x = f8enc(v.x); o.y = f8enc(v.y); o.z = f8enc(v.z); o.w = f8enc(v.w);
    ((uchar4*)x0)[i] = o;
}

// ---- bin pass: LDS multisplit -> line-aligned run-coalesced flush ---------
// Record: int2{ (v14<<18)|col , (b<<18)|row }. Runs rounded to 8 records
// (64B); sentinel pads {0,-1} written in flush phase (lines dirtied once).
__global__ void __launch_bounds__(256) bin_k(const int* __restrict__ rows,
                                             const int* __restrict__ cols,
                                             const float* __restrict__ vals,
                                             int* __restrict__ bcur,
                                             int2* __restrict__ brec) {
    __shared__ int2 stage[EPB];                    // 31.3 KB (sm overlays head)
    __shared__ int  lh[NBUCKET], gbase[NBUCKET];   // 1.6 KB
    __shared__ unsigned short lofs[NBUCKET];       // 0.4 KB
    int t = threadIdx.x;
    int* sm = (int*)stage;                         // scan scratch, dead before stage use
    int e0 = blockIdx.x * EPB;
    int e1 = e0 + EPB; if (e1 > NNZ_C) e1 = NNZ_C;
    for (int i = t; i < NBUCKET; i += 256) lh[i] = 0;
    __syncthreads();
    #pragma unroll 4
    for (int e = e0 + t; e < e1; e += 256)
        atomicAdd(&lh[rows[e] / RPB], 1);          // cached: re-read in scatter
    __syncthreads();
    {   // exclusive scan of lh -> lofs (NBUCKET=196 <= 256: 1 elem/thread)
        int ssum = (t < NBUCKET) ? lh[t] : 0;
        sm[t] = ssum;
        __syncthreads();
        for (int o = 1; o < 256; o <<= 1) {
            int v = (t >= o) ? sm[t - o] : 0;
            __syncthreads();
            sm[t] += v;
            __syncthreads();
        }
        if (t < NBUCKET) lofs[t] = (unsigned short)(sm[t] - ssum);
    }
    __syncthreads();
    for (int i = t; i < NBUCKET; i += 256) {
        int c = lh[i];
        if (c) {
            int c8 = (c + 7) & ~7;                      // line-align the run
            gbase[i] = atomicAdd(&bcur[i * 16], c8);
        }
        lh[i] = 0;
    }
    __syncthreads();
    #pragma unroll 2
    for (int e = e0 + t; e < e1; e += 256) {
        int   r = rows[e];                              // L2-warm (hist read)
        int   c = __builtin_nontemporal_load(cols + e);
        float v = __builtin_nontemporal_load(vals + e);
        int b = r / RPB;
        int rank = atomicAdd(&lh[b], 1);
        int j = (int)lofs[b] + rank;
        unsigned int v14 = (unsigned int)lrintf(v * 524288.0f);   // x 2^19
        if (v14 > 16383u) v14 = 16383u;
        stage[j] = make_int2((int)((v14 << 18) | (unsigned int)c),
                             (b << 18) | r);            // bucket packed in .y
    }
    __syncthreads();
    int cnt = e1 - e0;
    for (int j = t; j < cnt; j += 256) {
        int2 rc = stage[j];
        int b = (int)((unsigned int)rc.y >> 18);        // no div in flush
        brec[gbase[b] + (j - (int)lofs[b])] = rc;
    }
    // pad tails: written while the payload lines are still L2-dirty
    for (int i = t; i < NBUCKET; i += 256) {
        int c = lh[i];
        if (c) {
            int c8 = (c + 7) & ~7;
            int g  = gbase[i];
            for (int q = g + c; q < g + c8; ++q)
                brec[q] = make_int2(0, -1);
        }
    }
}

// ---- per-bucket reorder -> crec (rows padded to x8, zero-filled pads) -----
// 768-row buckets, 512 threads, 196 blocks = single generation.
__global__ void __launch_bounds__(512) csr_fix_k(const int2* __restrict__ brec,
                                                 const int* __restrict__ bcur,
                                                 unsigned int* __restrict__ crec,
                                                 int2* __restrict__ rp2) {
    __shared__ int lh[RPB], lb[RPB], lc[RPB], sm2[512];
    int b = blockIdx.x;
    int t = threadIdx.x;
    int s = b * CAP, e = bcur[b * 16];
    int cnt = e - s;
    int cb = b * CAPC;
    int rbase = b * RPB;
    for (int i = t; i < RPB; i += 512) lh[i] = 0;
    __syncthreads();
    for (int j = t; j < cnt; j += 512) {
        unsigned int rl = (unsigned int)((brec[s + j].y & 0x3FFFF) - rbase);
        if (rl < RPB) atomicAdd(&lh[rl], 1);         // sentinel pads skipped
    }
    __syncthreads();
    {   // exclusive scan of pad8 counts -> lb; write rp2, zero lc (K=2)
        int loc[2];
        int ssum = 0;
        #pragma unroll
        for (int k = 0; k < 2; ++k) {
            int i = t * 2 + k;
            loc[k] = (i < RPB) ? ((lh[i] + 7) & ~7) : 0;
            ssum += loc[k];
        }
        sm2[t] = ssum;
        __syncthreads();
        for (int o = 1; o < 512; o <<= 1) {
            int v = (t >= o) ? sm2[t - o] : 0;
            __syncthreads();
            sm2[t] += v;
            __syncthreads();
        }
        int run = sm2[t] - ssum;
        #pragma unroll
        for (int k = 0; k < 2; ++k) {
            int i = t * 2 + k;
            if (i < RPB) {
                lb[i] = run;
                lc[i] = 0;
                int row = rbase + i;
                if (row < NTOT) rp2[row] = make_int2(cb + run, cb + run + lh[i]);
            }
            run += loc[k];
        }
    }
    __syncthreads();
    for (int j = t; j < cnt; j += 512) {
        int2 rc = brec[s + j];
        unsigned int rl = (unsigned int)((rc.y & 0x3FFFF) - rbase);
        if (rl < RPB) {
            int pos = atomicAdd(&lc[rl], 1);
            crec[cb + lb[rl] + pos] = (unsigned int)rc.x;   // pre-quantized
        }
    }
    __syncthreads();
    // zero-fill pad slots [lh, cnt8) per row (disjoint from record writes)
    for (int i = t; i < RPB; i += 512) {
        int base = cb + lb[i];
        int c8 = (lh[i] + 7) & ~7;
        for (int q = lh[i]; q < c8; ++q) crec[base + q] = 0u;
    }
}

// ---- pull-mode SpMM body: wave = 4 edge-groups x 16 dim-lanes -------------
// Group g = lane>>4 owns record slots [j+8g, j+8g+8); lane&15 owns dim quad.
// Weights kept as integer-valued floats; 2^-19 scale folded into the store.
__device__ __forceinline__ void spmm_row_v4(const unsigned char* __restrict__ x,
                                            const unsigned int* __restrict__ crec,
                                            int s, int e, int lane, float* acc) {
    int g  = lane >> 4;
    int dq = (lane & 15) * 4;
    acc[0] = acc[1] = acc[2] = acc[3] = 0.0f;
    int e8 = s + ((e - s + 7) & ~7);         // padded end (zero records in pads)
    for (int j = s + 8 * g; j < e8; j += 32) {
        u32x4 pa = __builtin_nontemporal_load((const u32x4*)(crec + j));
        u32x4 pb = __builtin_nontemporal_load((const u32x4*)(crec + j + 4));
        unsigned int q0 = *(const unsigned int*)(x + (pa.x & 0x3FFFFu) * DIM + dq);
        unsigned int q1 = *(const unsigned int*)(x + (pa.y & 0x3FFFFu) * DIM + dq);
        unsigned int q2 = *(const unsigned int*)(x + (pa.z & 0x3FFFFu) * DIM + dq);
        unsigned int q3 = *(const unsigned int*)(x + (pa.w & 0x3FFFFu) * DIM + dq);
        unsigned int q4 = *(const unsigned int*)(x + (pb.x & 0x3FFFFu) * DIM + dq);
        unsigned int q5 = *(const unsigned int*)(x + (pb.y & 0x3FFFFu) * DIM + dq);
        unsigned int q6 = *(const unsigned int*)(x + (pb.z & 0x3FFFFu) * DIM + dq);
        unsigned int q7 = *(const unsigned int*)(x + (pb.w & 0x3FFFFu) * DIM + dq);
        float w0 = (float)(pa.x >> 18);
        float w1 = (float)(pa.y >> 18);
        float w2 = (float)(pa.z >> 18);
        float w3 = (float)(pa.w >> 18);
        float w4 = (float)(pb.x >> 18);
        float w5 = (float)(pb.y >> 18);
        float w6 = (float)(pb.z >> 18);
        float w7 = (float)(pb.w >> 18);
        fp8x4_fma(q0, w0, acc);
        fp8x4_fma(q1, w1, acc);
        fp8x4_fma(q2, w2, acc);
        fp8x4_fma(q3, w3, acc);
        fp8x4_fma(q4, w4, acc);
        fp8x4_fma(q5, w5, acc);
        fp8x4_fma(q6, w6, acc);
        fp8x4_fma(q7, w7, acc);
    }
    // combine the 4 edge-groups: butterfly over lane bits 4,5
    acc[0] += __shfl_xor(acc[0], 16, 64);
    acc[1] += __shfl_xor(acc[1], 16, 64);
    acc[2] += __shfl_xor(acc[2], 16, 64);
    acc[3] += __shfl_xor(acc[3], 16, 64);
    acc[0] += __shfl_xor(acc[0], 32, 64);
    acc[1] += __shfl_xor(acc[1], 32, 64);
    acc[2] += __shfl_xor(acc[2], 32, 64);
    acc[3] += __shfl_xor(acc[3], 32, 64);
}

__device__ __forceinline__ void spmm_store(unsigned char* __restrict__ y, int row,
                                           int lane, const float* acc) {
    if (lane < 16) {
        uchar4 o;
        o.x = f8enc(acc[0] * SCALE_ST);
        o.y = f8enc(acc[1] * SCALE_ST);
        o.z = f8enc(acc[2] * SCALE_ST);
        o.w = f8enc(acc[3] * SCALE_ST);
        *(uchar4*)(y + row * DIM + lane * 4) = o;
    }
}

// ---- full SpMM: one wave per row; output scaled x16 -----------------------
__global__ void spmm_k(const unsigned char* __restrict__ x, const int2* __restrict__ rp2,
                       const unsigned int* __restrict__ crec, unsigned char* __restrict__ y) {
    int row  = (blockIdx.x * blockDim.x + threadIdx.x) >> 6;
    int lane = threadIdx.x & 63;
    if (row >= NTOT) return;
    int2 se = rp2[row];
    float acc[4];
    spmm_row_v4(x, crec, se.x, se.y, lane, acc);
    spmm_store(y, row, lane, acc);
}

// ---- sliced SpMM for hop 3: only rows the loss reads ----------------------
__global__ void spmm_sliced_k(const unsigned char* __restrict__ x, const int2* __restrict__ rp2,
                              const unsigned int* __restrict__ crec,
                              const int* __restrict__ users, const int* __restrict__ items,
                              const int* __restrict__ negs, unsigned char* __restrict__ y) {
    int w    = (blockIdx.x * blockDim.x + threadIdx.x) >> 6;
    int lane = threadIdx.x & 63;
    if (w >= NSLICE) return;
    int row = (w < BATCH)     ? users[w]
            : (w < 2 * BATCH) ? NUM_USERS + items[w - BATCH]
                              : NUM_USERS + negs[w - 2 * BATCH];
    int2 se = rp2[row];
    float acc[4];
    spmm_row_v4(x, crec, se.x, se.y, lane, acc);
    spmm_store(y, row, lane, acc);   // duplicate rows rewrite same value: benign
}

// ---- InfoNCE loss; e = 0.25*(x0 + x1/16 + x2/256 + x3/4096) ---------------
// Atomic-free: per-block LDS reduce -> plain store to partials[block].
__global__ void loss_k(const unsigned char* __restrict__ x0, const unsigned char* __restrict__ x1,
                       const unsigned char* __restrict__ x2, const unsigned char* __restrict__ x3,
                       const int* __restrict__ users, const int* __restrict__ items,
                       const int* __restrict__ negs, float* __restrict__ partials) {
    __shared__ float psum[4];
    int w    = (blockIdx.x * blockDim.x + threadIdx.x) >> 6;
    int lane = threadIdx.x & 63;
    int wv   = threadIdx.x >> 6;
    float v = 0.0f;
    if (w < BATCH) {
        auto rowv = [&](int r) -> float {
            int o = r * DIM + lane;
            return 0.25f * f8dec(x0[o]) + 0.015625f * f8dec(x1[o]) +
                   9.765625e-4f * f8dec(x2[o]) + 6.103515625e-5f * f8dec(x3[o]);
        };
        float ue = rowv(users[w]);
        float ie = rowv(NUM_USERS + items[w]);
        float p = ue * ie;
        for (int o = 32; o > 0; o >>= 1) p += __shfl_xor(p, o, 64);
        float pe = expf(p);
        float ne = 0.0f;
        for (int k = 0; k < NUM_NEG; ++k) {
            float q = ue * rowv(NUM_USERS + negs[k * BATCH + w]);
            for (int o = 32; o > 0; o >>= 1) q += __shfl_xor(q, o, 64);
            ne += expf(q);
        }
        v = logf((pe + ne) / pe);
    }
    if (lane == 0) psum[wv] = v;
    __syncthreads();
    if (threadIdx.x == 0)
        partials[blockIdx.x] = psum[0] + psum[1] + psum[2] + psum[3];
}

// ---- final reduce: one block sums NLOSSB partials ------------------------
__global__ void finalize_k(const float* __restrict__ partials, float* __restrict__ out) {
    __shared__ float ps[4];
    int t = threadIdx.x;
    float s = 0.0f;
    for (int i = t; i < NLOSSB; i += 256) s += partials[i];
    for (int o = 32; o > 0; o >>= 1) s += __shfl_xor(s, o, 64);
    if ((t & 63) == 0) ps[t >> 6] = s;
    __syncthreads();
    if (t == 0) out[0] = (ps[0] + ps[1] + ps[2] + ps[3]) * (1.0f / BATCH);
}

__global__ void sentinel_k(float* __restrict__ out) {
    out[0] = -1.0f;
}

extern "C" void kernel_launch(void* const* d_in, const int* in_sizes, int n_in,
                              void* d_out, int out_size, void* d_ws, size_t ws_size,
                              hipStream_t stream) {
    const float* user_emb = (const float*)d_in[0];
    const float* item_emb = (const float*)d_in[1];
    const float* A_vals   = (const float*)d_in[2];
    const int*   A_rows   = (const int*)d_in[3];
    const int*   A_cols   = (const int*)d_in[4];
    const int*   users    = (const int*)d_in[5];
    const int*   items    = (const int*)d_in[6];
    const int*   negs     = (const int*)d_in[7];
    float* out = (float*)d_out;

    char* ws = (char*)d_ws;
    size_t off = 0;
    auto carve = [&](size_t bytes) -> char* {
        char* p = ws + off;
        off = (off + bytes + 255) & ~(size_t)255;
        return p;
    };
    unsigned char* x0 = (unsigned char*)carve((size_t)NTOT * DIM);    // 9.6 MB
    unsigned char* x1 = (unsigned char*)carve((size_t)NTOT * DIM);
    unsigned char* x2 = (unsigned char*)carve((size_t)NTOT * DIM);
    unsigned char* x3 = (unsigned char*)carve((size_t)NTOT * DIM);
    int2*  brec       = (int2*)carve((size_t)NBUCKET * CAP * 8);      // 40.1 MB
    unsigned int* crec= (unsigned int*)carve((size_t)NBUCKET * CAPC * 4 + 1024); // 19.5 MB
    int2*  rp2        = (int2*)carve((size_t)NTOT * 8);               //  1.2 MB
    int*   bcur       = (int*)carve((size_t)NBUCKET * 64);            // 64B-strided cursors
    float* partials   = (float*)carve((size_t)NLOSSB * 4);            // 4 KB

    if (off > ws_size) {
        sentinel_k<<<1, 1, 0, stream>>>(out);
        return;
    }

    convert_concat<<<(NTOT * DIM / 4 + 255) / 256, 256, 0, stream>>>(user_emb, item_emb, x0, bcur);

    // bucketed build: staged multisplit (line-aligned runs), then row reorder
    bin_k<<<BIN_BLOCKS, 256, 0, stream>>>(A_rows, A_cols, A_vals, bcur, brec);
    csr_fix_k<<<NBUCKET, 512, 0, stream>>>(brec, bcur, crec, rp2);

    // hops 1-2 full, hop 3 sliced to loss rows
    const int spmm_blocks = (NTOT * 64 + 255) / 256;
    spmm_k<<<spmm_blocks, 256, 0, stream>>>(x0, rp2, crec, x1);
    spmm_k<<<spmm_blocks, 256, 0, stream>>>(x1, rp2, crec, x2);
    spmm_sliced_k<<<(NSLICE * 64 + 255) / 256, 256, 0, stream>>>(x2, rp2, crec, users, items, negs, x3);

    // loss: block partials (no atomics) + single-block reduce
    loss_k<<<NLOSSB, 256, 0, stream>>>(x0, x1, x2, x3, users, items, negs, partials);
    finalize_k<<<1, 256, 0, stream>>>(partials, out);
}